// Round 5
// baseline (423.145 us; speedup 1.0000x reference)
//
#include <hip/hip_runtime.h>
#include <hip/hip_bf16.h>

// QuantizedLinear: out[64,8192] = x[64,8192] @ (alpha * ternary(W))^T + bias
// Round-5 change (single variable vs round 4): replace the 2-deep
// drain-vmcnt(0)-per-tile loop with a 4-deep LDS ring + raw s_barrier +
// COUNTED s_waitcnt vmcnt(9) (T3/T4, m201/m218 discipline). Per-wave
// global-load in-flight never drops below 3 tiles; no vmcnt(0) drain in
// the main loop. BK=32 tiles, 4 slots x 12 KB = 48 KB LDS (3 blocks/CU,
// 12 waves/CU -- same occupancy as r3/r4, pipeline 4x deeper).
// Staging/compute mapping, ternarize-on-read, partials+reduce epilogue are
// carried over from the verified round-4 kernel.

typedef __attribute__((ext_vector_type(8))) short short8;   // 8 bf16 = 4 VGPRs
typedef __attribute__((ext_vector_type(4))) float floatx4;  // MFMA acc

#define B_DIM 64
#define K_DIM 8192
#define O_DIM 8192
#define BN 64                      // W rows (output cols) per block
#define BK 32                      // k per tile
#define KSPLIT 8
#define KCHUNK (K_DIM / KSPLIT)    // 1024 k per block
#define NT (KCHUNK / BK)           // 32 tiles
#define DEPTH 4                    // ring depth
#define PART_STRIDE ((size_t)B_DIM * O_DIM)

__device__ __forceinline__ void gload_lds16(const void* g, void* l) {
  __builtin_amdgcn_global_load_lds(
      (const __attribute__((address_space(1))) void*)g,
      (__attribute__((address_space(3))) void*)l, 16, 0, 0);
}

// ---- prep: x fp32 -> bf16 workspace (vectorized) ----
__global__ __launch_bounds__(256) void prep_kernel(
    const float* __restrict__ x, __hip_bfloat16* __restrict__ xbf) {
  int idx = (blockIdx.x * 256 + threadIdx.x) * 8;
  float4 v0 = *(const float4*)(x + idx);
  float4 v1 = *(const float4*)(x + idx + 4);
  __hip_bfloat16 h[8];
  h[0] = __float2bfloat16(v0.x); h[1] = __float2bfloat16(v0.y);
  h[2] = __float2bfloat16(v0.z); h[3] = __float2bfloat16(v0.w);
  h[4] = __float2bfloat16(v1.x); h[5] = __float2bfloat16(v1.y);
  h[6] = __float2bfloat16(v1.z); h[7] = __float2bfloat16(v1.w);
  *(short8*)&xbf[idx] = *(const short8*)h;
}

// ---- main GEMM: 1024 blocks (128 n-tiles x 8 k-slices), 256 threads ----
__global__ __launch_bounds__(256, 3) void gemm_kernel(
    const float* __restrict__ w, const unsigned short* __restrict__ xbf,
    const float* __restrict__ alpha, float* __restrict__ part) {
  __shared__ __align__(16) float Ws[DEPTH][BN][BK];             // 32 KB
  __shared__ __align__(16) unsigned short Xs[DEPTH][B_DIM][BK]; // 16 KB

  const int tid = threadIdx.x;
  const int nt = blockIdx.x & 127;   // n-tile (fast dim)
  const int ks = blockIdx.x >> 7;    // k-slice 0..7
  const int n0 = nt * BN;
  const int k0 = ks * KCHUNK;

  const int wv  = tid >> 6;    // wave 0..3
  const int ln  = tid & 63;
  const int lhi = ln >> 4;     // 0..3 -> k-subgroup of 8
  const int llo = ln & 15;     // fragment row

  const int nrow = n0 + wv * 16 + llo;     // this lane's W row (output col)
  const float av  = alpha[nrow];
  const float thr = 0.5f * (av + 1e-8f);
  const int swW = (llo & 7) << 4;          // read-side XOR swizzle, W (bytes)
  const int swX = (llo & 3) << 4;          // read-side XOR swizzle, X (bytes)

  floatx4 acc[4];
#pragma unroll
  for (int i = 0; i < 4; ++i) acc[i] = (floatx4){0.f, 0.f, 0.f, 0.f};

  auto tern = [&](float v) -> short {
    return v > thr ? (short)0x3F80
                   : (v < -thr ? (short)(unsigned short)0xBF80 : (short)0);
  };

  // ---- stage one BK=32 tile into ring slot: 3 gload_lds16 per wave ----
  auto stage = [&](int slot, int kt) {
    const size_t kb = (size_t)(k0 + kt * BK);
    // W: 2 instrs/wave, 8 rows x 128 B each; source pre-swizzled within row.
#pragma unroll
    for (int j = 0; j < 2; ++j) {
      const int r0  = wv * 16 + j * 8;
      const int row = r0 + (ln >> 3);
      const char* src = (const char*)w
          + ((size_t)(n0 + row) * K_DIM + kb) * 4
          + (((ln & 7) * 16) ^ ((row & 7) << 4));
      gload_lds16(src, &Ws[slot][r0][0]);
    }
    // X: 1 instr/wave, 16 rows x 64 B; source pre-swizzled within row.
    {
      const int r0  = wv * 16;
      const int row = r0 + (ln >> 2);
      const char* src = (const char*)xbf
          + ((size_t)row * K_DIM + kb) * 2
          + (((ln & 3) * 16) ^ ((row & 3) << 4));
      gload_lds16(src, &Xs[slot][r0][0]);
    }
  };

  auto compute = [&](int slot) {
    const char* wrow = (const char*)&Ws[slot][wv * 16 + llo][0];   // 128 B row
    float4 f0 = *(const float4*)(wrow + ((lhi * 32)      ^ swW));
    float4 f1 = *(const float4*)(wrow + ((lhi * 32 + 16) ^ swW));
    short8 b;
    b[0] = tern(f0.x); b[1] = tern(f0.y); b[2] = tern(f0.z); b[3] = tern(f0.w);
    b[4] = tern(f1.x); b[5] = tern(f1.y); b[6] = tern(f1.z); b[7] = tern(f1.w);
#pragma unroll
    for (int mt = 0; mt < 4; ++mt) {
      const char* xrow = (const char*)&Xs[slot][mt * 16 + llo][0]; // 64 B row
      short8 a = *(const short8*)(xrow + ((lhi * 16) ^ swX));
      acc[mt] = __builtin_amdgcn_mfma_f32_16x16x32_bf16(a, b, acc[mt], 0, 0, 0);
    }
  };

  // ---- prologue: fill the ring 4 deep (12 loads/wave in flight) ----
#pragma unroll
  for (int p = 0; p < DEPTH; ++p) stage(p, p);

  // ---- main loop: counted vmcnt, raw barriers, NO vmcnt(0) drain ----
  for (int t = 0; t < NT; ++t) {
    const int rem = NT - 1 - t;    // tiles still issued beyond t
    if (rem >= 3)      asm volatile("s_waitcnt vmcnt(9)" ::: "memory");
    else if (rem == 2) asm volatile("s_waitcnt vmcnt(6)" ::: "memory");
    else if (rem == 1) asm volatile("s_waitcnt vmcnt(3)" ::: "memory");
    else               asm volatile("s_waitcnt vmcnt(0)" ::: "memory");
    __builtin_amdgcn_sched_barrier(0);
    __builtin_amdgcn_s_barrier();        // all waves' tile-t DMAs visible
    __builtin_amdgcn_sched_barrier(0);

    compute(t & (DEPTH - 1));

    __builtin_amdgcn_sched_barrier(0);
    __builtin_amdgcn_s_barrier();        // all waves done reading slot
    __builtin_amdgcn_sched_barrier(0);

    if (t + DEPTH < NT) stage(t & (DEPTH - 1), t + DEPTH);
  }

  // epilogue: C/D layout col=lane&15 (n), row=(lane>>4)*4+reg (m).
  // Plain stores into this k-slice's private partial plane.
  float* pout = part + (size_t)ks * PART_STRIDE;
#pragma unroll
  for (int mt = 0; mt < 4; ++mt) {
    const int m = mt * 16 + lhi * 4;
#pragma unroll
    for (int r = 0; r < 4; ++r) {
      pout[(size_t)(m + r) * O_DIM + nrow] = acc[mt][r] * av;
    }
  }
}

// ---- reduce: out = bias + sum_ks part[ks]; fully coalesced float4 ----
__global__ __launch_bounds__(256) void reduce_kernel(
    const float* __restrict__ part, const float* __restrict__ bias,
    float* __restrict__ out) {
  const size_t base = (size_t)(blockIdx.x * 256 + threadIdx.x) * 4;
  float4 s = *(const float4*)(bias + (base & (size_t)(O_DIM - 1)));
#pragma unroll
  for (int ks = 0; ks < KSPLIT; ++ks) {
    float4 p = *(const float4*)(part + ks * PART_STRIDE + base);
    s.x += p.x; s.y += p.y; s.z += p.z; s.w += p.w;
  }
  *(float4*)(out + base) = s;
}

extern "C" void kernel_launch(void* const* d_in, const int* in_sizes, int n_in,
                              void* d_out, int out_size, void* d_ws, size_t ws_size,
                              hipStream_t stream) {
  const float* x     = (const float*)d_in[0];  // [64, 8192]
  const float* w     = (const float*)d_in[1];  // [8192, 8192]
  const float* alpha = (const float*)d_in[2];  // [8192, 1]
  const float* bias  = (const float*)d_in[3];  // [8192]
  float* out = (float*)d_out;                  // [64, 8192]

  // workspace layout: [0, 16.8MB) partials, [32MB, 33MB) xbf
  float* part = (float*)d_ws;
  __hip_bfloat16* xbf = (__hip_bfloat16*)((char*)d_ws + (32u << 20));

  prep_kernel<<<(B_DIM * K_DIM) / (256 * 8), 256, 0, stream>>>(x, xbf);
  gemm_kernel<<<(O_DIM / BN) * KSPLIT, 256, 0, stream>>>(
      w, (const unsigned short*)xbf, alpha, part);
  reduce_kernel<<<(B_DIM * O_DIM) / (256 * 4), 256, 0, stream>>>(part, bias, out);
}

// Round 6
// 393.909 us; speedup vs baseline: 1.0742x; 1.0742x over previous
//
#include <hip/hip_runtime.h>
#include <hip/hip_bf16.h>

// QuantizedLinear: out[64,8192] = x[64,8192] @ (alpha * ternary(W))^T + bias
// Round-6 change (single variable vs r4/r5): tile geometry. Previous rounds
// read each W row in 128-256 B chunks (16-32 revisits/row, interleaved with
// ~10^4 other streams chip-wide -> every chunk pays a DRAM page activation;
// measured 0.9-1.0 TB/s effective vs 6.7 TB/s linear fill). New tile is
// [16 rows x 256 k]: every global_load_lds instruction reads 1 KB truly
// CONTIGUOUS within one W row (lane l -> base + l*16), rows consumed as 8
// back-to-back 1 KB bursts. Waves split K inside the block (r2-verified LDS
// reduction); X A-frags load direct from the L2-hot 1 MB bf16 workspace;
// 2-slot 32 KB LDS ring; KSPLIT=4 + partials/reduce epilogue from r4.

typedef __attribute__((ext_vector_type(8))) short short8;   // 8 bf16 = 4 VGPRs
typedef __attribute__((ext_vector_type(4))) float floatx4;  // MFMA acc

#define B_DIM 64
#define K_DIM 8192
#define O_DIM 8192
#define BN 16                      // W rows (output cols) per block
#define BKT 256                    // k per tile
#define KSPLIT 4
#define KCHUNK (K_DIM / KSPLIT)    // 2048 k per block
#define NT (KCHUNK / BKT)          // 8 tiles
#define NWAVE 4
#define SLOT_BYTES (BN * BKT * 4)  // 16 KB per ring slot
#define PART_STRIDE ((size_t)B_DIM * O_DIM)

__device__ __forceinline__ void gload_lds16(const void* g, void* l) {
  __builtin_amdgcn_global_load_lds(
      (const __attribute__((address_space(1))) void*)g,
      (__attribute__((address_space(3))) void*)l, 16, 0, 0);
}

// ---- prep: x fp32 -> bf16 workspace (vectorized) ----
__global__ __launch_bounds__(256) void prep_kernel(
    const float* __restrict__ x, __hip_bfloat16* __restrict__ xbf) {
  int idx = (blockIdx.x * 256 + threadIdx.x) * 8;
  float4 v0 = *(const float4*)(x + idx);
  float4 v1 = *(const float4*)(x + idx + 4);
  __hip_bfloat16 h[8];
  h[0] = __float2bfloat16(v0.x); h[1] = __float2bfloat16(v0.y);
  h[2] = __float2bfloat16(v0.z); h[3] = __float2bfloat16(v0.w);
  h[4] = __float2bfloat16(v1.x); h[5] = __float2bfloat16(v1.y);
  h[6] = __float2bfloat16(v1.z); h[7] = __float2bfloat16(v1.w);
  *(short8*)&xbf[idx] = *(const short8*)h;
}

// ---- main GEMM: 2048 blocks (512 n-tiles x 4 k-slices), 256 threads ----
__global__ __launch_bounds__(256, 4) void gemm_kernel(
    const float* __restrict__ w, const unsigned short* __restrict__ xbf,
    const float* __restrict__ alpha, float* __restrict__ part) {
  __shared__ __align__(16) char smem[2 * SLOT_BYTES];   // 32 KB ring; reused for reduction

  const int tid = threadIdx.x;
  const int nt = blockIdx.x & 511;   // n-tile (fast dim)
  const int ks = blockIdx.x >> 9;    // k-slice 0..3
  const int n0 = nt * BN;
  const int k0 = ks * KCHUNK;

  const int wv  = tid >> 6;    // wave 0..3 -> k-subslice within tile
  const int ln  = tid & 63;
  const int lhi = ln >> 4;     // 0..3
  const int llo = ln & 15;     // fragment row (W row within tile)

  const int nrow = n0 + llo;                // this lane's W row (output col)
  const float av  = alpha[nrow];
  const float thr = 0.5f * (av + 1e-8f);    // |w| > 0.5*(alpha+eps) -> +/-1
  const int sw = (llo & 7) << 4;            // read-side XOR swizzle (bytes)

  floatx4 acc[4];
#pragma unroll
  for (int i = 0; i < 4; ++i) acc[i] = (floatx4){0.f, 0.f, 0.f, 0.f};

  auto tern = [&](float v) -> short {
    return v > thr ? (short)0x3F80
                   : (v < -thr ? (short)(unsigned short)0xBF80 : (short)0);
  };

  // ---- stage: 4 instrs/wave, each = ONE ROW x 1 KB contiguous ----
  auto stage = [&](int slot, int kt) {
    const size_t kb = (size_t)(k0 + kt * BKT);
#pragma unroll
    for (int j = 0; j < 4; ++j) {
      const int row = wv * 4 + j;
      const char* src = (const char*)w
          + ((size_t)(n0 + row) * K_DIM + kb) * 4
          + ((ln * 16) ^ ((row & 7) << 4));           // pre-swizzled source
      gload_lds16(src, smem + slot * SLOT_BYTES + row * 1024);
    }
  };

  // ---- compute one [16 x 256] tile: wave wv owns k-window wv*64..+64 ----
  auto compute = [&](int slot, int kt) {
    const char* base = smem + slot * SLOT_BYTES + llo * 1024;
#pragma unroll
    for (int step = 0; step < 2; ++step) {
      const int c = wv * 256 + step * 128 + lhi * 32;  // byte offset in row
      float4 f0 = *(const float4*)(base + ((c)      ^ sw));
      float4 f1 = *(const float4*)(base + ((c + 16) ^ sw));
      short8 b;
      b[0] = tern(f0.x); b[1] = tern(f0.y); b[2] = tern(f0.z); b[3] = tern(f0.w);
      b[4] = tern(f1.x); b[5] = tern(f1.y); b[6] = tern(f1.z); b[7] = tern(f1.w);
      const size_t kglob = (size_t)k0 + kt * BKT + wv * 64 + step * 32 + lhi * 8;
#pragma unroll
      for (int mt = 0; mt < 4; ++mt) {
        short8 a = *(const short8*)(const void*)
            (xbf + (size_t)(mt * 16 + llo) * K_DIM + kglob);
        acc[mt] = __builtin_amdgcn_mfma_f32_16x16x32_bf16(a, b, acc[mt], 0, 0, 0);
      }
    }
  };

  stage(0, 0);
  __syncthreads();                 // tile 0 resident
  int buf = 0;
  for (int t = 0; t < NT; ++t) {
    if (t + 1 < NT) stage(buf ^ 1, t + 1);  // async, overlaps compute
    compute(buf, t);
    __syncthreads();               // reads of buf done + buf^1 landed
    buf ^= 1;
  }

  // ---- cross-wave k-reduction (r2-verified), reusing the ring LDS ----
  float (*red)[4][64][4] = (float (*)[4][64][4])smem;   // 16 KB
#pragma unroll
  for (int mt = 0; mt < 4; ++mt)
    *(floatx4*)&red[wv][mt][ln][0] = acc[mt];
  __syncthreads();

  floatx4 s = *(const floatx4*)&red[0][wv][ln][0];
#pragma unroll
  for (int w2 = 1; w2 < NWAVE; ++w2) {
    floatx4 t = *(const floatx4*)&red[w2][wv][ln][0];
    s[0] += t[0]; s[1] += t[1]; s[2] += t[2]; s[3] += t[3];
  }

  // C/D layout: col = lane&15 (n), row = (lane>>4)*4 + reg (m); alpha in fp32.
  float* pout = part + (size_t)ks * PART_STRIDE;
  const int mbase = wv * 16 + lhi * 4;
#pragma unroll
  for (int r = 0; r < 4; ++r) {
    pout[(size_t)(mbase + r) * O_DIM + nrow] = s[r] * av;
  }
}

// ---- reduce: out = bias + sum_ks part[ks]; fully coalesced float4 ----
__global__ __launch_bounds__(256) void reduce_kernel(
    const float* __restrict__ part, const float* __restrict__ bias,
    float* __restrict__ out) {
  const size_t base = (size_t)(blockIdx.x * 256 + threadIdx.x) * 4;
  float4 s = *(const float4*)(bias + (base & (size_t)(O_DIM - 1)));
#pragma unroll
  for (int ks = 0; ks < KSPLIT; ++ks) {
    float4 p = *(const float4*)(part + ks * PART_STRIDE + base);
    s.x += p.x; s.y += p.y; s.z += p.z; s.w += p.w;
  }
  *(float4*)(out + base) = s;
}

extern "C" void kernel_launch(void* const* d_in, const int* in_sizes, int n_in,
                              void* d_out, int out_size, void* d_ws, size_t ws_size,
                              hipStream_t stream) {
  const float* x     = (const float*)d_in[0];  // [64, 8192]
  const float* w     = (const float*)d_in[1];  // [8192, 8192]
  const float* alpha = (const float*)d_in[2];  // [8192, 1]
  const float* bias  = (const float*)d_in[3];  // [8192]
  float* out = (float*)d_out;                  // [64, 8192]

  // workspace layout: [0, 8.4MB) partials, [32MB, 33MB) xbf
  float* part = (float*)d_ws;
  __hip_bfloat16* xbf = (__hip_bfloat16*)((char*)d_ws + (32u << 20));

  prep_kernel<<<(B_DIM * K_DIM) / (256 * 8), 256, 0, stream>>>(x, xbf);
  gemm_kernel<<<(O_DIM / BN) * KSPLIT, 256, 0, stream>>>(
      w, (const unsigned short*)xbf, alpha, part);
  reduce_kernel<<<(B_DIM * O_DIM) / (256 * 4), 256, 0, stream>>>(part, bias, out);
}